// Round 3
// baseline (276.716 us; speedup 1.0000x reference)
//
#include <hip/hip_runtime.h>
#include <stdint.h>

typedef __attribute__((ext_vector_type(4))) float f32x4;
typedef __attribute__((ext_vector_type(8))) float f32x8;
typedef __attribute__((ext_vector_type(16))) float f32x16;
typedef __attribute__((ext_vector_type(8))) short bf16x8;
typedef __attribute__((ext_vector_type(4))) short s16x4;
typedef __attribute__((ext_vector_type(4))) int i32x4;
typedef __attribute__((ext_vector_type(2))) int i32x2;

#define DEVI static __device__ __forceinline__

constexpr int CB  = 4;     // batch
constexpr int CS  = 2048;  // seq
constexpr int CH  = 16;    // heads
constexpr int CDH = 64;    // head dim
constexpr int CE  = 1024;  // embed

DEVI short f2bf(float x) {  // RNE float->bf16 (epilogue use)
  unsigned u = __float_as_uint(x);
  u += 0x7fffu + ((u >> 16) & 1u);
  return (short)(u >> 16);
}

DEVI int cvtpk(float lo, float hi) {  // packed f32x2 -> bf16x2 (RNE, 1 inst)
  int r;
  asm("v_cvt_pk_bf16_f32 %0, %1, %2" : "=v"(r) : "v"(lo), "v"(hi));
  return r;
}

DEVI float exp2v(float x) {  // raw v_exp_f32 (2^x)
  float r;
  asm("v_exp_f32 %0, %1" : "=v"(r) : "v"(x));
  return r;
}

DEVI float rcpv(float x) {  // v_rcp_f32 (~1 ulp)
  float r;
  asm("v_rcp_f32 %0, %1" : "=v"(r) : "v"(x));
  return r;
}

DEVI void gload16(const void* g, void* l) {
  __builtin_amdgcn_global_load_lds(
      (const __attribute__((address_space(1))) void*)g,
      (__attribute__((address_space(3))) void*)l, 16, 0, 0);
}

DEVI f32x4 mfma16(bf16x8 a, bf16x8 b, f32x4 c) {
  return __builtin_amdgcn_mfma_f32_16x16x32_bf16(a, b, c, 0, 0, 0);
}
DEVI f32x16 mfma32(bf16x8 a, bf16x8 b, f32x16 c) {
  return __builtin_amdgcn_mfma_f32_32x32x16_bf16(a, b, c, 0, 0, 0);
}

DEVI float rmax16(f32x16 v) {
  f32x8 a = __builtin_shufflevector(v, v, 0, 1, 2, 3, 4, 5, 6, 7);
  f32x8 b = __builtin_shufflevector(v, v, 8, 9, 10, 11, 12, 13, 14, 15);
  a = __builtin_elementwise_max(a, b);
  f32x4 c = __builtin_shufflevector(a, a, 0, 1, 2, 3);
  f32x4 d = __builtin_shufflevector(a, a, 4, 5, 6, 7);
  c = __builtin_elementwise_max(c, d);
  return fmaxf(fmaxf(c[0], c[1]), fmaxf(c[2], c[3]));
}

// ---------------- fp32 -> bf16 conversion passes ----------------

__global__ __launch_bounds__(256) void cvt_f32_bf16(
    const float* __restrict__ in, short* __restrict__ out, int n8) {
  int i = blockIdx.x * 256 + threadIdx.x;
  if (i >= n8) return;
  size_t o = (size_t)i * 8;
  f32x4 a = *(const f32x4*)&in[o];
  f32x4 b = *(const f32x4*)&in[o + 4];
  i32x4 p = {cvtpk(a[0], a[1]), cvtpk(a[2], a[3]),
             cvtpk(b[0], b[1]), cvtpk(b[2], b[3])};
  *(i32x4*)&out[o] = p;
}

__global__ __launch_bounds__(256) void cvtW3(
    const float* __restrict__ w0, const float* __restrict__ w1,
    const float* __restrict__ w2, short* __restrict__ o0,
    short* __restrict__ o1, short* __restrict__ o2) {
  const float* in = blockIdx.y == 0 ? w0 : (blockIdx.y == 1 ? w1 : w2);
  short* out = blockIdx.y == 0 ? o0 : (blockIdx.y == 1 ? o1 : o2);
  size_t o = ((size_t)blockIdx.x * 256 + threadIdx.x) * 8;
  f32x4 a = *(const f32x4*)&in[o];
  f32x4 b = *(const f32x4*)&in[o + 4];
  i32x4 p = {cvtpk(a[0], a[1]), cvtpk(a[2], a[3]),
             cvtpk(b[0], b[1]), cvtpk(b[2], b[3])};
  *(i32x4*)&out[o] = p;
}

// ---------------- GEMM: C = A(bf16) * W^T + bias ----------------
// WB16=1: W already bf16 (gload16 staging). WB16=0: W fp32, convert in-flight.
// MODE 0: out fp32 [M,N]; MODE 1: out bf16 [B,H,S,DH] scaled; MODE 2: [B,H,DH,S]
template<int MODE, int WB16>
__global__ __launch_bounds__(256) void gemm_bt(
    const short* __restrict__ Ap, const void* __restrict__ Wp,
    const float* __restrict__ bias, void* __restrict__ outp,
    int M, int N, int K, float scale) {
  __shared__ short As[128 * 32];
  __shared__ short Bs[128 * 32];
  const int t  = threadIdx.x;
  const int l  = t & 63;
  const int w  = t >> 6;
  const int g  = l >> 4;
  const int ln = l & 15;
  const int m0 = blockIdx.y * 128;
  const int n0 = blockIdx.x * 128;
  const int wr = (w >> 1) * 64;
  const int wc = (w & 1) * 64;

  f32x4 acc[4][4];
#pragma unroll
  for (int i = 0; i < 4; ++i)
#pragma unroll
    for (int j = 0; j < 4; ++j) acc[i][j] = {0.f, 0.f, 0.f, 0.f};

  for (int kt = 0; kt < K; kt += 32) {
#pragma unroll
    for (int il = 0; il < 2; ++il) {
      int o = (w * 2 + il) * 1024 + l * 16;
      int row = o >> 6, cb = o & 63;
      gload16((const char*)Ap + ((size_t)(m0 + row) * K + kt) * 2 + cb,
              (char*)As + o);
      if constexpr (WB16) {
        gload16((const char*)Wp + ((size_t)(n0 + row) * K + kt) * 2 + cb,
                (char*)Bs + o);
      }
    }
    if constexpr (!WB16) {
      const float* W = (const float*)Wp;
#pragma unroll
      for (int i = 0; i < 4; ++i) {
        int c = (i << 8) + t;
        int row = c >> 3, col = (c & 7) << 2;
        f32x4 v = *(const f32x4*)&W[(size_t)(n0 + row) * K + kt + col];
        i32x2 pw = {cvtpk(v[0], v[1]), cvtpk(v[2], v[3])};
        *(i32x2*)&Bs[row * 32 + col] = pw;
      }
    }
    __syncthreads();

    bf16x8 af[4], bfr[4];
#pragma unroll
    for (int mi = 0; mi < 4; ++mi)
      af[mi] = *(const bf16x8*)&As[(wr + mi * 16 + ln) * 32 + g * 8];
#pragma unroll
    for (int ni = 0; ni < 4; ++ni)
      bfr[ni] = *(const bf16x8*)&Bs[(wc + ni * 16 + ln) * 32 + g * 8];
#pragma unroll
    for (int mi = 0; mi < 4; ++mi)
#pragma unroll
      for (int ni = 0; ni < 4; ++ni)
        acc[mi][ni] = mfma16(af[mi], bfr[ni], acc[mi][ni]);
    __syncthreads();
  }

  // C/D (16x16): col = lane&15, row = (lane>>4)*4 + reg
#pragma unroll
  for (int mi = 0; mi < 4; ++mi)
#pragma unroll
    for (int ni = 0; ni < 4; ++ni)
#pragma unroll
      for (int r = 0; r < 4; ++r) {
        int row = m0 + wr + mi * 16 + g * 4 + r;
        int col = n0 + wc + ni * 16 + ln;
        float v = acc[mi][ni][r] + bias[col];
        if constexpr (MODE == 0) {
          ((float*)outp)[(size_t)row * N + col] = v;
        } else if constexpr (MODE == 1) {
          int b = row >> 11, s = row & 2047, h = col >> 6, d = col & 63;
          ((short*)outp)[(((size_t)(b * CH + h)) * CS + s) * CDH + d] =
              f2bf(v * scale);
        } else {
          int b = row >> 11, s = row & 2047, h = col >> 6, d = col & 63;
          ((short*)outp)[(((size_t)(b * CH + h)) * CDH + d) * CS + s] =
              f2bf(v * scale);
        }
      }
}

// ---------------- Flash attention, 32x32 MFMA, 32 q/wave ----------------
// q: [BH,S,DH] bf16 pre-scaled by log2e/8. k: [BH,S,DH]. vt: [BH,DH,S].
// out: [B,S,E] bf16. Swapped QK^T (mfma(K,Q)): lane holds 32 scores for its
// q-col (lane&31); P feeds PV A-operand with zero cross-lane movement.
// Row-sums via ones-column MFMA (accS) - rescales identically to accO, so no
// lrun/rsum/epilogue shuffles. K LDS: XOR-swizzle via pre-swizzled gload16
// source. V LDS: kv-dim bit-permuted so P's kv set reads as contiguous b128.
__global__ __launch_bounds__(256, 3) void attn_fwd(
    const short* __restrict__ qp, const short* __restrict__ kp,
    const short* __restrict__ vtp, short* __restrict__ outp) {
  __shared__ short Ks[2][64 * 64];
  __shared__ short Vs[2][64 * 64];
  const int t = threadIdx.x, l = t & 63, w = t >> 6;
  const int lo = l & 31, hi = l >> 5;
  const int qb = blockIdx.x, bh = blockIdx.y, b = bh >> 4, h = bh & 15;
  const int swl = (lo & 7) << 4;

  // Q fragments: wave w owns q rows qb*128 + w*32 .. +31
  const short* qbase = qp + ((size_t)bh * CS + qb * 128 + w * 32) * CDH;
  bf16x8 qf[4];
#pragma unroll
  for (int ks = 0; ks < 4; ++ks)
    qf[ks] = *(const bf16x8*)&qbase[lo * CDH + ks * 16 + hi * 8];

  // K staging: thread t DMAs rows t>>3 and t>>3+32, src pre-swizzled
  const int krow = t >> 3, kcb = (t & 7) * 16;
  const char* ksrc = (const char*)kp + (size_t)bh * CS * 128 +
                     (size_t)krow * 128 + (kcb ^ ((krow & 7) << 4));
  // V staging (reg): thread t covers d-row t>>2, kv chunks (t&3) and (t&3)+4
  const int vrow = t >> 2, vc = t & 3;
  const char* vbase = (const char*)vtp + (size_t)bh * CDH * (CS * 2) +
                      (size_t)vrow * (CS * 2) + vc * 16;
  const int vsw = (vrow & 7) << 4;
  const int vgb = (vc >> 1) * 32 + (vc & 1) * 8;
  const int vw0 = vgb ^ vsw, vw1 = (vgb + 16) ^ vsw;
  const int vw2 = (vgb + 64) ^ vsw, vw3 = (vgb + 80) ^ vsw;

  const bf16x8 ones = {0x3F80, 0x3F80, 0x3F80, 0x3F80,
                       0x3F80, 0x3F80, 0x3F80, 0x3F80};

  f32x16 accO[2] = {};  // [nb] output, rows = q
  f32x16 accS = {};     // row-sums (all cols identical)
  float mrun = -1e30f;

  // prologue: stage tile 0 into buf 0
  {
    gload16(ksrc, (char*)&Ks[0][0] + t * 16);
    gload16(ksrc + 4096, (char*)&Ks[0][0] + t * 16 + 4096);
    i32x4 v0 = *(const i32x4*)vbase;
    i32x4 v1 = *(const i32x4*)(vbase + 64);
    char* vd = (char*)&Vs[0][0] + vrow * 128;
    *(i32x2*)(vd + vw0) = __builtin_shufflevector(v0, v0, 0, 1);
    *(i32x2*)(vd + vw1) = __builtin_shufflevector(v0, v0, 2, 3);
    *(i32x2*)(vd + vw2) = __builtin_shufflevector(v1, v1, 0, 1);
    *(i32x2*)(vd + vw3) = __builtin_shufflevector(v1, v1, 2, 3);
  }
  __syncthreads();

#pragma unroll 2
  for (int tl = 0; tl < 32; ++tl) {
    const int cur = tl & 1, nxt = cur ^ 1;
    const char* Kc = (const char*)&Ks[cur][0];
    const char* Vc = (const char*)&Vs[cur][0];
    const bool last = (tl == 31);
    i32x4 v0, v1;
    if (!last) {  // issue next-tile loads early (T14)
      const char* ks2 = ksrc + (size_t)(tl + 1) * 8192;
      gload16(ks2, (char*)&Ks[nxt][0] + t * 16);
      gload16(ks2 + 4096, (char*)&Ks[nxt][0] + t * 16 + 4096);
      v0 = *(const i32x4*)(vbase + (size_t)(tl + 1) * 128);
      v1 = *(const i32x4*)(vbase + (size_t)(tl + 1) * 128 + 64);
    }

    // QK^T swapped: D[kv][q]; sc[mb], lane col = q = lo
    f32x16 sc[2] = {};
    __builtin_amdgcn_s_setprio(1);
#pragma unroll
    for (int mb = 0; mb < 2; ++mb) {
      const char* krp = Kc + (mb * 32 + lo) * 128;
#pragma unroll
      for (int ks = 0; ks < 4; ++ks) {
        bf16x8 kf = *(const bf16x8*)(krp + ((ks * 32 + hi * 16) ^ swl));
        sc[mb] = mfma32(kf, qf[ks], sc[mb]);
      }
    }
    __builtin_amdgcn_s_setprio(0);

    // online softmax (log2 domain), defer-max THR=12
    float pm = rmax16(__builtin_elementwise_max(sc[0], sc[1]));
    pm = fmaxf(pm, __shfl_xor(pm, 32, 64));
    if (__any(pm > mrun + 12.f)) {
      float mn = fmaxf(mrun, pm);
      float fc = exp2v(mrun - mn);
      f32x16 fv;
#pragma unroll
      for (int r = 0; r < 16; ++r)
        fv[r] = __shfl(fc, (r & 3) + 8 * (r >> 2) + 4 * hi, 64);
      accO[0] *= fv;
      accO[1] *= fv;
      accS *= fv;
      mrun = mn;
    }
    // exp in place: sc := P
#pragma unroll
    for (int mb = 0; mb < 2; ++mb)
#pragma unroll
      for (int i = 0; i < 16; ++i) sc[mb][i] = exp2v(sc[mb][i] - mrun);

    // pack P -> bf16 A-fragments: frag[kst] slot s <-> sc[kst>>1][(kst&1)*8+s]
    bf16x8 pf[4];
#pragma unroll
    for (int kst = 0; kst < 4; ++kst) {
      const int mb = kst >> 1, o8 = (kst & 1) * 8;
      i32x4 pw = {cvtpk(sc[mb][o8 + 0], sc[mb][o8 + 1]),
                  cvtpk(sc[mb][o8 + 2], sc[mb][o8 + 3]),
                  cvtpk(sc[mb][o8 + 4], sc[mb][o8 + 5]),
                  cvtpk(sc[mb][o8 + 6], sc[mb][o8 + 7])};
      pf[kst] = __builtin_bit_cast(bf16x8, pw);
    }

    // PV: D[q][d]; B = permuted Vt rows. Plus ones-column row-sum.
    __builtin_amdgcn_s_setprio(1);
#pragma unroll
    for (int nb = 0; nb < 2; ++nb) {
      const char* vrp = Vc + (nb * 32 + lo) * 128;
#pragma unroll
      for (int kst = 0; kst < 4; ++kst) {
        bf16x8 vf = *(const bf16x8*)(vrp + ((kst * 32 + hi * 16) ^ swl));
        accO[nb] = mfma32(pf[kst], vf, accO[nb]);
      }
    }
#pragma unroll
    for (int kst = 0; kst < 4; ++kst) accS = mfma32(pf[kst], ones, accS);
    __builtin_amdgcn_s_setprio(0);

    if (!last) {  // write next V tile (loads have landed under compute)
      char* vd = (char*)&Vs[nxt][0] + vrow * 128;
      *(i32x2*)(vd + vw0) = __builtin_shufflevector(v0, v0, 0, 1);
      *(i32x2*)(vd + vw1) = __builtin_shufflevector(v0, v0, 2, 3);
      *(i32x2*)(vd + vw2) = __builtin_shufflevector(v1, v1, 0, 1);
      *(i32x2*)(vd + vw3) = __builtin_shufflevector(v1, v1, 2, 3);
    }
    __syncthreads();
  }

  // epilogue: normalize (per-reg rcp of accS row-sum) and store
  f32x16 iv;
#pragma unroll
  for (int r = 0; r < 16; ++r) iv[r] = rcpv(accS[r]);
#pragma unroll
  for (int nb = 0; nb < 2; ++nb) {
    f32x16 val = accO[nb] * iv;
#pragma unroll
    for (int r = 0; r < 16; ++r) {
      int sg = qb * 128 + w * 32 + (r & 3) + 8 * (r >> 2) + 4 * hi;
      outp[((size_t)(b * CS + sg)) * CE + h * CDH + nb * 32 + lo] =
          f2bf(val[r]);
    }
  }
}

extern "C" void kernel_launch(void* const* d_in, const int* in_sizes, int n_in,
                              void* d_out, int out_size, void* d_ws,
                              size_t ws_size, hipStream_t stream) {
  const float* queries = (const float*)d_in[0];
  const float* keys    = (const float*)d_in[1];
  const float* values  = (const float*)d_in[2];
  const float* Wq = (const float*)d_in[3];
  const float* bq = (const float*)d_in[4];
  const float* Wk = (const float*)d_in[5];
  const float* bk = (const float*)d_in[6];
  const float* Wv = (const float*)d_in[7];
  const float* bv = (const float*)d_in[8];
  const float* Wo = (const float*)d_in[9];
  const float* bo = (const float*)d_in[10];

  const size_t NELT = (size_t)CB * CS * CE;  // 8388608
  short* R1  = (short*)d_ws;        // X16 scratch, later attn output
  short* qp  = R1 + NELT;
  short* kp  = qp + NELT;
  short* vtp = kp + NELT;
  // W16 scratch lives in d_out (dead until the final GEMM overwrites it)
  short* w16q = (short*)d_out;
  short* w16k = w16q + (size_t)CE * CE;
  short* w16v = w16k + (size_t)CE * CE;

  dim3 blk(256);
  dim3 gproj(CE / 128, (CB * CS) / 128);  // (8, 64)
  const int n8x = (int)(NELT / 8);        // 1048576
  const float qscale = 0.18033688011112042f;  // log2(e) / sqrt(DH)

  cvtW3<<<dim3(512, 3), blk, 0, stream>>>(Wq, Wk, Wv, w16q, w16k, w16v);
  cvt_f32_bf16<<<4096, blk, 0, stream>>>(queries, R1, n8x);
  gemm_bt<1, 1><<<gproj, blk, 0, stream>>>(R1, w16q, bq, qp,
                                           CB * CS, CE, CE, qscale);
  cvt_f32_bf16<<<4096, blk, 0, stream>>>(keys, R1, n8x);
  gemm_bt<1, 1><<<gproj, blk, 0, stream>>>(R1, w16k, bk, kp,
                                           CB * CS, CE, CE, 1.0f);
  cvt_f32_bf16<<<4096, blk, 0, stream>>>(values, R1, n8x);
  gemm_bt<2, 1><<<gproj, blk, 0, stream>>>(R1, w16v, bv, vtp,
                                           CB * CS, CE, CE, 1.0f);
  attn_fwd<<<dim3(CS / 128, CB * CH), blk, 0, stream>>>(qp, kp, vtp, R1);
  gemm_bt<0, 0><<<gproj, blk, 0, stream>>>(R1, Wo, bo, (float*)d_out,
                                           CB * CS, CE, CE, 1.0f);
}

// Round 4
// 244.355 us; speedup vs baseline: 1.1324x; 1.1324x over previous
//
#include <hip/hip_runtime.h>
#include <stdint.h>

typedef __attribute__((ext_vector_type(4))) float f32x4;
typedef __attribute__((ext_vector_type(8))) float f32x8;
typedef __attribute__((ext_vector_type(16))) float f32x16;
typedef __attribute__((ext_vector_type(8))) short bf16x8;
typedef __attribute__((ext_vector_type(4))) int i32x4;
typedef __attribute__((ext_vector_type(2))) int i32x2;

#define DEVI static __device__ __forceinline__

constexpr int CB  = 4;     // batch
constexpr int CS  = 2048;  // seq
constexpr int CH  = 16;    // heads
constexpr int CDH = 64;    // head dim
constexpr int CE  = 1024;  // embed

DEVI short f2bf(float x) {  // RNE float->bf16 (epilogue use)
  unsigned u = __float_as_uint(x);
  u += 0x7fffu + ((u >> 16) & 1u);
  return (short)(u >> 16);
}

DEVI int cvtpk(float lo, float hi) {  // packed f32x2 -> bf16x2 (RNE, 1 inst)
  int r;
  asm("v_cvt_pk_bf16_f32 %0, %1, %2" : "=v"(r) : "v"(lo), "v"(hi));
  return r;
}

DEVI float exp2v(float x) {  // raw v_exp_f32 (2^x)
  float r;
  asm("v_exp_f32 %0, %1" : "=v"(r) : "v"(x));
  return r;
}

DEVI float rcpv(float x) {  // v_rcp_f32 (~1 ulp)
  float r;
  asm("v_rcp_f32 %0, %1" : "=v"(r) : "v"(x));
  return r;
}

DEVI void gload16(const void* g, void* l) {
  __builtin_amdgcn_global_load_lds(
      (const __attribute__((address_space(1))) void*)g,
      (__attribute__((address_space(3))) void*)l, 16, 0, 0);
}

DEVI f32x4 mfma16(bf16x8 a, bf16x8 b, f32x4 c) {
  return __builtin_amdgcn_mfma_f32_16x16x32_bf16(a, b, c, 0, 0, 0);
}
DEVI f32x16 mfma32(bf16x8 a, bf16x8 b, f32x16 c) {
  return __builtin_amdgcn_mfma_f32_32x32x16_bf16(a, b, c, 0, 0, 0);
}

DEVI float rmax16(f32x16 v) {
  f32x8 a = __builtin_shufflevector(v, v, 0, 1, 2, 3, 4, 5, 6, 7);
  f32x8 b = __builtin_shufflevector(v, v, 8, 9, 10, 11, 12, 13, 14, 15);
  a = __builtin_elementwise_max(a, b);
  f32x4 c = __builtin_shufflevector(a, a, 0, 1, 2, 3);
  f32x4 d = __builtin_shufflevector(a, a, 4, 5, 6, 7);
  c = __builtin_elementwise_max(c, d);
  return fmaxf(fmaxf(c[0], c[1]), fmaxf(c[2], c[3]));
}

// ---------------- W fp32 -> bf16 (once; reused by 3 projections) ------------

__global__ __launch_bounds__(256) void cvtW3(
    const float* __restrict__ w0, const float* __restrict__ w1,
    const float* __restrict__ w2, short* __restrict__ o0,
    short* __restrict__ o1, short* __restrict__ o2) {
  const float* in = blockIdx.y == 0 ? w0 : (blockIdx.y == 1 ? w1 : w2);
  short* out = blockIdx.y == 0 ? o0 : (blockIdx.y == 1 ? o1 : o2);
  size_t o = ((size_t)blockIdx.x * 256 + threadIdx.x) * 8;
  f32x4 a = *(const f32x4*)&in[o];
  f32x4 b = *(const f32x4*)&in[o + 4];
  i32x4 p = {cvtpk(a[0], a[1]), cvtpk(a[2], a[3]),
             cvtpk(b[0], b[1]), cvtpk(b[2], b[3])};
  *(i32x4*)&out[o] = p;
}

// ---------------- GEMM: C = A * W^T + bias ----------------
// AB16: A bf16 (gload16) vs fp32 (convert during staging).
// WB16: W bf16 (gload16) vs fp32 (convert during staging).
// MODE 0: out fp32 [M,N]; MODE 1: out bf16 [B,H,S,DH] scaled;
// MODE 2: out bf16 [B,H,DH,S] with kv bits2,3 swapped per 16-block (so the
//         attention V tile can be staged linearly by global_load_lds).
// Grid: 1D 512 blocks, XCD-chunk swizzled (8 XCDs x 64 blocks; each XCD gets
// 8 row-panels x all 8 col-tiles -> A panel + W resident in its L2).
template<int MODE, int AB16, int WB16>
__global__ __launch_bounds__(256) void gemm_bt(
    const void* __restrict__ Ap, const void* __restrict__ Wp,
    const float* __restrict__ bias, void* __restrict__ outp,
    int M, int N, int K, float scale) {
  __shared__ short As[128 * 32];
  __shared__ short Bs[128 * 32];
  const int t  = threadIdx.x;
  const int l  = t & 63;
  const int w  = t >> 6;
  const int g  = l >> 4;
  const int ln = l & 15;
  const int lin = blockIdx.x;
  const int wg = (lin & 7) * 64 + (lin >> 3);
  const int n0 = (wg & 7) * 128;
  const int m0 = (wg >> 3) * 128;
  const int wr = (w >> 1) * 64;
  const int wc = (w & 1) * 64;

  f32x4 acc[4][4];
#pragma unroll
  for (int i = 0; i < 4; ++i)
#pragma unroll
    for (int j = 0; j < 4; ++j) acc[i][j] = {0.f, 0.f, 0.f, 0.f};

  for (int kt = 0; kt < K; kt += 32) {
#pragma unroll
    for (int il = 0; il < 2; ++il) {
      int o = (w * 2 + il) * 1024 + l * 16;
      int row = o >> 6, cb = o & 63;
      if constexpr (AB16) {
        gload16((const char*)Ap + ((size_t)(m0 + row) * K + kt) * 2 + cb,
                (char*)As + o);
      }
      if constexpr (WB16) {
        gload16((const char*)Wp + ((size_t)(n0 + row) * K + kt) * 2 + cb,
                (char*)Bs + o);
      }
    }
    if constexpr (!AB16) {
      const float* A = (const float*)Ap;
#pragma unroll
      for (int i = 0; i < 4; ++i) {
        int c = (i << 8) + t;
        int row = c >> 3, col = (c & 7) << 2;
        f32x4 v = *(const f32x4*)&A[(size_t)(m0 + row) * K + kt + col];
        i32x2 pw = {cvtpk(v[0], v[1]), cvtpk(v[2], v[3])};
        *(i32x2*)&As[row * 32 + col] = pw;
      }
    }
    if constexpr (!WB16) {
      const float* W = (const float*)Wp;
#pragma unroll
      for (int i = 0; i < 4; ++i) {
        int c = (i << 8) + t;
        int row = c >> 3, col = (c & 7) << 2;
        f32x4 v = *(const f32x4*)&W[(size_t)(n0 + row) * K + kt + col];
        i32x2 pw = {cvtpk(v[0], v[1]), cvtpk(v[2], v[3])};
        *(i32x2*)&Bs[row * 32 + col] = pw;
      }
    }
    __syncthreads();

    bf16x8 af[4], bfr[4];
#pragma unroll
    for (int mi = 0; mi < 4; ++mi)
      af[mi] = *(const bf16x8*)&As[(wr + mi * 16 + ln) * 32 + g * 8];
#pragma unroll
    for (int ni = 0; ni < 4; ++ni)
      bfr[ni] = *(const bf16x8*)&Bs[(wc + ni * 16 + ln) * 32 + g * 8];
#pragma unroll
    for (int mi = 0; mi < 4; ++mi)
#pragma unroll
      for (int ni = 0; ni < 4; ++ni)
        acc[mi][ni] = mfma16(af[mi], bfr[ni], acc[mi][ni]);
    __syncthreads();
  }

  // C/D (16x16): col = lane&15, row = (lane>>4)*4 + reg
#pragma unroll
  for (int mi = 0; mi < 4; ++mi)
#pragma unroll
    for (int ni = 0; ni < 4; ++ni)
#pragma unroll
      for (int r = 0; r < 4; ++r) {
        int row = m0 + wr + mi * 16 + g * 4 + r;
        int col = n0 + wc + ni * 16 + ln;
        float v = acc[mi][ni][r] + bias[col];
        if constexpr (MODE == 0) {
          ((float*)outp)[(size_t)row * N + col] = v;
        } else if constexpr (MODE == 1) {
          int b = row >> 11, s = row & 2047, h = col >> 6, d = col & 63;
          ((short*)outp)[(((size_t)(b * CH + h)) * CS + s) * CDH + d] =
              f2bf(v * scale);
        } else {
          int b = row >> 11, s = row & 2047, h = col >> 6, d = col & 63;
          int sp = (s & ~12) | ((s & 4) << 1) | ((s & 8) >> 1);  // swap b2,b3
          ((short*)outp)[(((size_t)(b * CH + h)) * CDH + d) * CS + sp] =
              f2bf(v * scale);
        }
      }
}

// ---------------- Flash attention, 32x32 MFMA, 64 q/wave ----------------
// q: [BH,S,DH] bf16 pre-scaled by log2e/8. k: [BH,S,DH]. vt: [BH,DH,S] with
// kv bits2,3 pre-swapped (MODE 2). out: [B,S,E] bf16.
// Swapped QK^T (mfma(K,Q)): lane holds 32 scores per qk-half for its q col
// (lane&31); P feeds PV A-operand with zero cross-lane movement. Row-sums via
// ones-column MFMA (accS). K and V both staged by global_load_lds with
// XOR-swizzled source chunks (linear LDS dest). Grid: 1D 512, XCD-chunked so
// each XCD keeps 8 bh worth of K/V (4MB) in its L2.
__global__ __launch_bounds__(256, 2) void attn_fwd(
    const short* __restrict__ qp, const short* __restrict__ kp,
    const short* __restrict__ vtp, short* __restrict__ outp) {
  __shared__ short Ks[2][64 * 64];
  __shared__ short Vs[2][64 * 64];
  const int t = threadIdx.x, l = t & 63, w = t >> 6;
  const int lo = l & 31, hi = l >> 5;
  const int lin = blockIdx.x;
  const int wg = (lin & 7) * 64 + (lin >> 3);
  const int qb = wg & 7, bh = wg >> 3;
  const int b = bh >> 4, h = bh & 15;
  const int swl = (lo & 7) << 4;

  // Q fragments: wave w owns q rows qb*256 + w*64 .. +63 (2 blocks of 32)
  const short* qbase = qp + ((size_t)bh * CS + qb * 256 + w * 64) * CDH;
  bf16x8 qf[2][4];
#pragma unroll
  for (int qk = 0; qk < 2; ++qk)
#pragma unroll
    for (int ks = 0; ks < 4; ++ks)
      qf[qk][ks] =
          *(const bf16x8*)&qbase[(qk * 32 + lo) * CDH + ks * 16 + hi * 8];

  // Staging sources (pre-XOR-swizzled chunk within each 128B row)
  const int srow = t >> 3;
  const int soff = ((t & 7) * 16) ^ ((srow & 7) << 4);
  const char* kb = (const char*)kp + (size_t)bh * CS * 128;
  const char* vb = (const char*)vtp + (size_t)bh * CDH * (CS * 2);
  const char* ksrc0 = kb + (size_t)srow * 128 + soff;
  const char* ksrc1 = kb + (size_t)(srow + 32) * 128 + soff;
  const char* vsrc0 = vb + (size_t)srow * (CS * 2) + soff;
  const char* vsrc1 = vb + (size_t)(srow + 32) * (CS * 2) + soff;

  const bf16x8 ones = {0x3F80, 0x3F80, 0x3F80, 0x3F80,
                       0x3F80, 0x3F80, 0x3F80, 0x3F80};

  f32x16 accO[2][2] = {};  // [qk][nb]
  f32x16 accS[2] = {};     // [qk] row-sums
  float mrun[2] = {-1e30f, -1e30f};

  // prologue: stage tile 0 into buf 0
  gload16(ksrc0, (char*)&Ks[0][0] + t * 16);
  gload16(ksrc1, (char*)&Ks[0][0] + t * 16 + 4096);
  gload16(vsrc0, (char*)&Vs[0][0] + t * 16);
  gload16(vsrc1, (char*)&Vs[0][0] + t * 16 + 4096);
  __syncthreads();

#pragma unroll 2
  for (int tl = 0; tl < 32; ++tl) {
    const int cur = tl & 1, nxt = cur ^ 1;
    const char* Kc = (const char*)&Ks[cur][0];
    const char* Vc = (const char*)&Vs[cur][0];
    if (tl != 31) {  // issue next-tile loads; they land under this compute
      size_t ko = (size_t)(tl + 1) * 8192;
      size_t vo = (size_t)(tl + 1) * 128;
      gload16(ksrc0 + ko, (char*)&Ks[nxt][0] + t * 16);
      gload16(ksrc1 + ko, (char*)&Ks[nxt][0] + t * 16 + 4096);
      gload16(vsrc0 + vo, (char*)&Vs[nxt][0] + t * 16);
      gload16(vsrc1 + vo, (char*)&Vs[nxt][0] + t * 16 + 4096);
    }

    // QK^T swapped: D[kv][q]; sc[qk][mb], lane col = q = qk*32+lo
    f32x16 sc[2][2] = {};
    __builtin_amdgcn_s_setprio(1);
#pragma unroll
    for (int mb = 0; mb < 2; ++mb) {
      const char* krp = Kc + (mb * 32 + lo) * 128;
#pragma unroll
      for (int ks = 0; ks < 4; ++ks) {
        bf16x8 kf = *(const bf16x8*)(krp + ((ks * 32 + hi * 16) ^ swl));
        sc[0][mb] = mfma32(kf, qf[0][ks], sc[0][mb]);
        sc[1][mb] = mfma32(kf, qf[1][ks], sc[1][mb]);
      }
    }
    __builtin_amdgcn_s_setprio(0);

    // online softmax (log2 domain), defer-max THR=12
    float pm0 = rmax16(__builtin_elementwise_max(sc[0][0], sc[0][1]));
    float pm1 = rmax16(__builtin_elementwise_max(sc[1][0], sc[1][1]));
    pm0 = fmaxf(pm0, __shfl_xor(pm0, 32, 64));
    pm1 = fmaxf(pm1, __shfl_xor(pm1, 32, 64));
    if (__any((pm0 > mrun[0] + 12.f) || (pm1 > mrun[1] + 12.f))) {
      float mn0 = fmaxf(mrun[0], pm0), mn1 = fmaxf(mrun[1], pm1);
      float fc0 = exp2v(mrun[0] - mn0), fc1 = exp2v(mrun[1] - mn1);
      f32x16 fv0, fv1;
#pragma unroll
      for (int r = 0; r < 16; ++r) {
        int src = (r & 3) + 8 * (r >> 2) + 4 * hi;
        fv0[r] = __shfl(fc0, src, 64);
        fv1[r] = __shfl(fc1, src, 64);
      }
      accO[0][0] *= fv0; accO[0][1] *= fv0; accS[0] *= fv0;
      accO[1][0] *= fv1; accO[1][1] *= fv1; accS[1] *= fv1;
      mrun[0] = mn0; mrun[1] = mn1;
    }
    // exp in place: sc := P
#pragma unroll
    for (int qk = 0; qk < 2; ++qk)
#pragma unroll
      for (int mb = 0; mb < 2; ++mb)
#pragma unroll
        for (int i = 0; i < 16; ++i)
          sc[qk][mb][i] = exp2v(sc[qk][mb][i] - mrun[qk]);

    // pack P -> bf16 A-fragments: frag[kst] slot s <-> sc[qk][kst>>1][(kst&1)*8+s]
    bf16x8 pf[2][4];
#pragma unroll
    for (int qk = 0; qk < 2; ++qk)
#pragma unroll
      for (int kst = 0; kst < 4; ++kst) {
        const int mb = kst >> 1, o8 = (kst & 1) * 8;
        i32x4 pw = {cvtpk(sc[qk][mb][o8 + 0], sc[qk][mb][o8 + 1]),
                    cvtpk(sc[qk][mb][o8 + 2], sc[qk][mb][o8 + 3]),
                    cvtpk(sc[qk][mb][o8 + 4], sc[qk][mb][o8 + 5]),
                    cvtpk(sc[qk][mb][o8 + 6], sc[qk][mb][o8 + 7])};
        pf[qk][kst] = __builtin_bit_cast(bf16x8, pw);
      }

    // PV: D[q][d]; B = V rows (kv order pre-permuted). Plus ones row-sums.
    __builtin_amdgcn_s_setprio(1);
#pragma unroll
    for (int nb = 0; nb < 2; ++nb) {
      const char* vrp = Vc + (nb * 32 + lo) * 128;
#pragma unroll
      for (int kst = 0; kst < 4; ++kst) {
        bf16x8 vf = *(const bf16x8*)(vrp + ((kst * 32 + hi * 16) ^ swl));
        accO[0][nb] = mfma32(pf[0][kst], vf, accO[0][nb]);
        accO[1][nb] = mfma32(pf[1][kst], vf, accO[1][nb]);
      }
    }
#pragma unroll
    for (int kst = 0; kst < 4; ++kst) {
      accS[0] = mfma32(pf[0][kst], ones, accS[0]);
      accS[1] = mfma32(pf[1][kst], ones, accS[1]);
    }
    __builtin_amdgcn_s_setprio(0);
    __syncthreads();
  }

  // epilogue: normalize (per-reg rcp of accS row-sum) and store
#pragma unroll
  for (int qk = 0; qk < 2; ++qk) {
    f32x16 iv;
#pragma unroll
    for (int r = 0; r < 16; ++r) iv[r] = rcpv(accS[qk][r]);
#pragma unroll
    for (int nb = 0; nb < 2; ++nb) {
      f32x16 val = accO[qk][nb] * iv;
#pragma unroll
      for (int r = 0; r < 16; ++r) {
        int sg = qb * 256 + w * 64 + qk * 32 + (r & 3) + 8 * (r >> 2) + 4 * hi;
        outp[((size_t)(b * CS + sg)) * CE + h * CDH + nb * 32 + lo] =
            f2bf(val[r]);
      }
    }
  }
}

extern "C" void kernel_launch(void* const* d_in, const int* in_sizes, int n_in,
                              void* d_out, int out_size, void* d_ws,
                              size_t ws_size, hipStream_t stream) {
  const float* queries = (const float*)d_in[0];
  const float* keys    = (const float*)d_in[1];
  const float* values  = (const float*)d_in[2];
  const float* Wq = (const float*)d_in[3];
  const float* bq = (const float*)d_in[4];
  const float* Wk = (const float*)d_in[5];
  const float* bk = (const float*)d_in[6];
  const float* Wv = (const float*)d_in[7];
  const float* bv = (const float*)d_in[8];
  const float* Wo = (const float*)d_in[9];
  const float* bo = (const float*)d_in[10];

  const size_t NELT = (size_t)CB * CS * CE;  // 8388608
  short* R1  = (short*)d_ws;        // attn output (bf16 [B,S,E])
  short* qp  = R1 + NELT;
  short* kp  = qp + NELT;
  short* vtp = kp + NELT;
  // W16 scratch lives in d_out (dead until the final GEMM overwrites it)
  short* w16q = (short*)d_out;
  short* w16k = w16q + (size_t)CE * CE;
  short* w16v = w16k + (size_t)CE * CE;

  dim3 blk(256);
  const float qscale = 0.18033688011112042f;  // log2(e) / sqrt(DH)

  cvtW3<<<dim3(512, 3), blk, 0, stream>>>(Wq, Wk, Wv, w16q, w16k, w16v);
  gemm_bt<1, 0, 1><<<512, blk, 0, stream>>>(queries, w16q, bq, qp,
                                            CB * CS, CE, CE, qscale);
  gemm_bt<1, 0, 1><<<512, blk, 0, stream>>>(keys, w16k, bk, kp,
                                            CB * CS, CE, CE, 1.0f);
  gemm_bt<2, 0, 1><<<512, blk, 0, stream>>>(values, w16v, bv, vtp,
                                            CB * CS, CE, CE, 1.0f);
  attn_fwd<<<512, blk, 0, stream>>>(qp, kp, vtp, R1);
  gemm_bt<0, 1, 0><<<512, blk, 0, stream>>>(R1, Wo, bo, (float*)d_out,
                                            CB * CS, CE, CE, 1.0f);
}

// Round 5
// 227.144 us; speedup vs baseline: 1.2182x; 1.0758x over previous
//
#include <hip/hip_runtime.h>
#include <stdint.h>

typedef __attribute__((ext_vector_type(4))) float f32x4;
typedef __attribute__((ext_vector_type(8))) float f32x8;
typedef __attribute__((ext_vector_type(16))) float f32x16;
typedef __attribute__((ext_vector_type(8))) short bf16x8;
typedef __attribute__((ext_vector_type(4))) int i32x4;
typedef __attribute__((ext_vector_type(2))) int i32x2;

#define DEVI static __device__ __forceinline__

constexpr int CB  = 4;     // batch
constexpr int CS  = 2048;  // seq
constexpr int CH  = 16;    // heads
constexpr int CDH = 64;    // head dim
constexpr int CE  = 1024;  // embed

DEVI short f2bf(float x) {  // RNE float->bf16 (epilogue use)
  unsigned u = __float_as_uint(x);
  u += 0x7fffu + ((u >> 16) & 1u);
  return (short)(u >> 16);
}

DEVI int cvtpk(float lo, float hi) {  // packed f32x2 -> bf16x2 (RNE, 1 inst)
  int r;
  asm("v_cvt_pk_bf16_f32 %0, %1, %2" : "=v"(r) : "v"(lo), "v"(hi));
  return r;
}

DEVI float exp2v(float x) {  // raw v_exp_f32 (2^x)
  float r;
  asm("v_exp_f32 %0, %1" : "=v"(r) : "v"(x));
  return r;
}

DEVI float rcpv(float x) {  // v_rcp_f32 (~1 ulp)
  float r;
  asm("v_rcp_f32 %0, %1" : "=v"(r) : "v"(x));
  return r;
}

DEVI void gload16(const void* g, void* l) {
  __builtin_amdgcn_global_load_lds(
      (const __attribute__((address_space(1))) void*)g,
      (__attribute__((address_space(3))) void*)l, 16, 0, 0);
}

DEVI f32x4 mfma16(bf16x8 a, bf16x8 b, f32x4 c) {
  return __builtin_amdgcn_mfma_f32_16x16x32_bf16(a, b, c, 0, 0, 0);
}
DEVI f32x16 mfma32(bf16x8 a, bf16x8 b, f32x16 c) {
  return __builtin_amdgcn_mfma_f32_32x32x16_bf16(a, b, c, 0, 0, 0);
}

DEVI float rmax16(f32x16 v) {
  f32x8 a = __builtin_shufflevector(v, v, 0, 1, 2, 3, 4, 5, 6, 7);
  f32x8 b = __builtin_shufflevector(v, v, 8, 9, 10, 11, 12, 13, 14, 15);
  a = __builtin_elementwise_max(a, b);
  f32x4 c = __builtin_shufflevector(a, a, 0, 1, 2, 3);
  f32x4 d = __builtin_shufflevector(a, a, 4, 5, 6, 7);
  c = __builtin_elementwise_max(c, d);
  return fmaxf(fmaxf(c[0], c[1]), fmaxf(c[2], c[3]));
}

// ---------------- W fp32 -> bf16 (once; reused by 3 projections) ------------

__global__ __launch_bounds__(256) void cvtW3(
    const float* __restrict__ w0, const float* __restrict__ w1,
    const float* __restrict__ w2, short* __restrict__ o0,
    short* __restrict__ o1, short* __restrict__ o2) {
  const float* in = blockIdx.y == 0 ? w0 : (blockIdx.y == 1 ? w1 : w2);
  short* out = blockIdx.y == 0 ? o0 : (blockIdx.y == 1 ? o1 : o2);
  size_t o = ((size_t)blockIdx.x * 256 + threadIdx.x) * 8;
  f32x4 a = *(const f32x4*)&in[o];
  f32x4 b = *(const f32x4*)&in[o + 4];
  i32x4 p = {cvtpk(a[0], a[1]), cvtpk(a[2], a[3]),
             cvtpk(b[0], b[1]), cvtpk(b[2], b[3])};
  *(i32x4*)&out[o] = p;
}

// ---------------- Fused Q/K/V projection GEMM ----------------
// y = blockIdx.y selects {A, W(bf16), bias, out, mode, scale}.
// C = A(fp32, converted in staging) * W^T + bias.
// mode 1 (y=0,1): out bf16 [B,H,S,DH] (q scaled by log2e/8, k unit)
// mode 2 (y=2):   out bf16 [B,H,DH,S], kv bits2,3 swapped per 16-block
// 3x512 blocks resident together -> ~6 waves/SIMD (vs 2 when launched alone).
__global__ __launch_bounds__(256, 4) void gemm_qkv(
    const float* __restrict__ A0, const float* __restrict__ A1,
    const float* __restrict__ A2, const short* __restrict__ W0,
    const short* __restrict__ W1, const short* __restrict__ W2,
    const float* __restrict__ b0, const float* __restrict__ b1,
    const float* __restrict__ b2, short* __restrict__ o0,
    short* __restrict__ o1, short* __restrict__ o2, float qscale) {
  __shared__ short As[128 * 32];
  __shared__ short Bs[128 * 32];
  const int y = blockIdx.y;
  const float* A = y == 0 ? A0 : (y == 1 ? A1 : A2);
  const short* W = y == 0 ? W0 : (y == 1 ? W1 : W2);
  const float* bias = y == 0 ? b0 : (y == 1 ? b1 : b2);
  short* outp = y == 0 ? o0 : (y == 1 ? o1 : o2);
  const float scale = y == 0 ? qscale : 1.0f;
  const int K = CE;

  const int t  = threadIdx.x;
  const int l  = t & 63;
  const int w  = t >> 6;
  const int g  = l >> 4;
  const int ln = l & 15;
  const int lin = blockIdx.x;
  const int wg = (lin & 7) * 64 + (lin >> 3);
  const int n0 = (wg & 7) * 128;
  const int m0 = (wg >> 3) * 128;
  const int wr = (w >> 1) * 64;
  const int wc = (w & 1) * 64;

  f32x4 acc[4][4];
#pragma unroll
  for (int i = 0; i < 4; ++i)
#pragma unroll
    for (int j = 0; j < 4; ++j) acc[i][j] = {0.f, 0.f, 0.f, 0.f};

  for (int kt = 0; kt < K; kt += 32) {
#pragma unroll
    for (int il = 0; il < 2; ++il) {
      int o = (w * 2 + il) * 1024 + l * 16;
      int row = o >> 6, cb = o & 63;
      gload16((const char*)W + ((size_t)(n0 + row) * K + kt) * 2 + cb,
              (char*)Bs + o);
    }
#pragma unroll
    for (int i = 0; i < 4; ++i) {
      int c = (i << 8) + t;
      int row = c >> 3, col = (c & 7) << 2;
      f32x4 v = *(const f32x4*)&A[(size_t)(m0 + row) * K + kt + col];
      i32x2 pw = {cvtpk(v[0], v[1]), cvtpk(v[2], v[3])};
      *(i32x2*)&As[row * 32 + col] = pw;
    }
    __syncthreads();

    bf16x8 af[4], bfr[4];
#pragma unroll
    for (int mi = 0; mi < 4; ++mi)
      af[mi] = *(const bf16x8*)&As[(wr + mi * 16 + ln) * 32 + g * 8];
#pragma unroll
    for (int ni = 0; ni < 4; ++ni)
      bfr[ni] = *(const bf16x8*)&Bs[(wc + ni * 16 + ln) * 32 + g * 8];
#pragma unroll
    for (int mi = 0; mi < 4; ++mi)
#pragma unroll
      for (int ni = 0; ni < 4; ++ni)
        acc[mi][ni] = mfma16(af[mi], bfr[ni], acc[mi][ni]);
    __syncthreads();
  }

#pragma unroll
  for (int mi = 0; mi < 4; ++mi)
#pragma unroll
    for (int ni = 0; ni < 4; ++ni)
#pragma unroll
      for (int r = 0; r < 4; ++r) {
        int row = m0 + wr + mi * 16 + g * 4 + r;
        int col = n0 + wc + ni * 16 + ln;
        float v = (acc[mi][ni][r] + bias[col]) * scale;
        int b = row >> 11, s = row & 2047, h = col >> 6, d = col & 63;
        if (y != 2) {
          outp[(((size_t)(b * CH + h)) * CS + s) * CDH + d] = f2bf(v);
        } else {
          int sp = (s & ~12) | ((s & 4) << 1) | ((s & 8) >> 1);  // swap b2,b3
          outp[(((size_t)(b * CH + h)) * CDH + d) * CS + sp] = f2bf(v);
        }
      }
}

// ---------------- Output GEMM: fp32 out = A(bf16)*W^T(fp32 cvt) + b ---------
__global__ __launch_bounds__(256) void gemm_out(
    const short* __restrict__ Ap, const float* __restrict__ Wp,
    const float* __restrict__ bias, float* __restrict__ outp, int K) {
  __shared__ short As[128 * 32];
  __shared__ short Bs[128 * 32];
  const int t  = threadIdx.x;
  const int l  = t & 63;
  const int w  = t >> 6;
  const int g  = l >> 4;
  const int ln = l & 15;
  const int lin = blockIdx.x;
  const int wg = (lin & 7) * 64 + (lin >> 3);
  const int n0 = (wg & 7) * 128;
  const int m0 = (wg >> 3) * 128;
  const int wr = (w >> 1) * 64;
  const int wc = (w & 1) * 64;

  f32x4 acc[4][4];
#pragma unroll
  for (int i = 0; i < 4; ++i)
#pragma unroll
    for (int j = 0; j < 4; ++j) acc[i][j] = {0.f, 0.f, 0.f, 0.f};

  for (int kt = 0; kt < K; kt += 32) {
#pragma unroll
    for (int il = 0; il < 2; ++il) {
      int o = (w * 2 + il) * 1024 + l * 16;
      int row = o >> 6, cb = o & 63;
      gload16((const char*)Ap + ((size_t)(m0 + row) * K + kt) * 2 + cb,
              (char*)As + o);
    }
#pragma unroll
    for (int i = 0; i < 4; ++i) {
      int c = (i << 8) + t;
      int row = c >> 3, col = (c & 7) << 2;
      f32x4 v = *(const f32x4*)&Wp[(size_t)(n0 + row) * K + kt + col];
      i32x2 pw = {cvtpk(v[0], v[1]), cvtpk(v[2], v[3])};
      *(i32x2*)&Bs[row * 32 + col] = pw;
    }
    __syncthreads();

    bf16x8 af[4], bfr[4];
#pragma unroll
    for (int mi = 0; mi < 4; ++mi)
      af[mi] = *(const bf16x8*)&As[(wr + mi * 16 + ln) * 32 + g * 8];
#pragma unroll
    for (int ni = 0; ni < 4; ++ni)
      bfr[ni] = *(const bf16x8*)&Bs[(wc + ni * 16 + ln) * 32 + g * 8];
#pragma unroll
    for (int mi = 0; mi < 4; ++mi)
#pragma unroll
      for (int ni = 0; ni < 4; ++ni)
        acc[mi][ni] = mfma16(af[mi], bfr[ni], acc[mi][ni]);
    __syncthreads();
  }

#pragma unroll
  for (int mi = 0; mi < 4; ++mi)
#pragma unroll
    for (int ni = 0; ni < 4; ++ni)
#pragma unroll
      for (int r = 0; r < 4; ++r) {
        int row = m0 + wr + mi * 16 + g * 4 + r;
        int col = n0 + wc + ni * 16 + ln;
        outp[(size_t)row * CE + col] = acc[mi][ni][r] + bias[col];
      }
}

// ---------------- Flash attention, 2-stream pipelined ----------------
// Streams A/B = the two independent 32-q halves of a wave's 64 q-rows.
// Per tile: stage(t+2,t+1) -> QK(B,t) || SMPV(A,t) -> QK(A,t+1) || SMPV(B,t).
// Each softmax's VALU overlaps an independent QK MFMA cluster in-wave.
// K: 4-ring LDS, V: 2-ring (48KB). Everything else as round 4 (XOR swizzle
// via pre-swizzled gload16 source, accS ones-MFMA row-sums, XCD swizzle).
struct AttnCtx {
  int lo, hi, swl;
};

DEVI void qk_half(const char* Kc, const bf16x8 qfh[4], f32x16 sc[2],
                  const AttnCtx& c) {
#pragma unroll
  for (int mb = 0; mb < 2; ++mb) {
    const char* krp = Kc + (mb * 32 + c.lo) * 128;
#pragma unroll
    for (int ks = 0; ks < 4; ++ks) {
      bf16x8 kf = *(const bf16x8*)(krp + ((ks * 32 + c.hi * 16) ^ c.swl));
      sc[mb] = mfma32(kf, qfh[ks], sc[mb]);
    }
  }
}

DEVI void smpv_half(f32x16 sc[2], const char* Vc, f32x16 accO[2],
                    f32x16& accS, float& mrun, const bf16x8& ones,
                    const AttnCtx& c) {
  float pm = rmax16(__builtin_elementwise_max(sc[0], sc[1]));
  pm = fmaxf(pm, __shfl_xor(pm, 32, 64));
  if (__any(pm > mrun + 12.f)) {  // defer-max (T13)
    float mn = fmaxf(mrun, pm);
    float fc = exp2v(mrun - mn);
    f32x16 fv;
#pragma unroll
    for (int r = 0; r < 16; ++r)
      fv[r] = __shfl(fc, (r & 3) + 8 * (r >> 2) + 4 * c.hi, 64);
    accO[0] *= fv;
    accO[1] *= fv;
    accS *= fv;
    mrun = mn;
  }
#pragma unroll
  for (int mb = 0; mb < 2; ++mb)
#pragma unroll
    for (int i = 0; i < 16; ++i) sc[mb][i] = exp2v(sc[mb][i] - mrun);

  bf16x8 pf[4];
#pragma unroll
  for (int kst = 0; kst < 4; ++kst) {
    const int mb = kst >> 1, o8 = (kst & 1) * 8;
    i32x4 pw = {cvtpk(sc[mb][o8 + 0], sc[mb][o8 + 1]),
                cvtpk(sc[mb][o8 + 2], sc[mb][o8 + 3]),
                cvtpk(sc[mb][o8 + 4], sc[mb][o8 + 5]),
                cvtpk(sc[mb][o8 + 6], sc[mb][o8 + 7])};
    pf[kst] = __builtin_bit_cast(bf16x8, pw);
  }
#pragma unroll
  for (int nb = 0; nb < 2; ++nb) {
    const char* vrp = Vc + (nb * 32 + c.lo) * 128;
#pragma unroll
    for (int kst = 0; kst < 4; ++kst) {
      bf16x8 vf = *(const bf16x8*)(vrp + ((kst * 32 + c.hi * 16) ^ c.swl));
      accO[nb] = mfma32(pf[kst], vf, accO[nb]);
    }
  }
#pragma unroll
  for (int kst = 0; kst < 4; ++kst) accS = mfma32(pf[kst], ones, accS);
}

__global__ __launch_bounds__(256, 2) void attn_fwd(
    const short* __restrict__ qp, const short* __restrict__ kp,
    const short* __restrict__ vtp, short* __restrict__ outp) {
  __shared__ short Ks[4][64 * 64];  // 4-ring
  __shared__ short Vs[2][64 * 64];  // 2-ring
  const int tid = threadIdx.x, l = tid & 63, w = tid >> 6;
  const int lo = l & 31, hi = l >> 5;
  const int lin = blockIdx.x;
  const int wg = (lin & 7) * 64 + (lin >> 3);
  const int qb = wg & 7, bh = wg >> 3;
  const int b = bh >> 4, h = bh & 15;
  const AttnCtx ctx = {lo, hi, (lo & 7) << 4};

  // Q fragments: wave w owns q rows qb*256 + w*64 .. +63 (streams A,B = 32 ea)
  const short* qbase = qp + ((size_t)bh * CS + qb * 256 + w * 64) * CDH;
  bf16x8 qf[2][4];
#pragma unroll
  for (int qk = 0; qk < 2; ++qk)
#pragma unroll
    for (int ks = 0; ks < 4; ++ks)
      qf[qk][ks] =
          *(const bf16x8*)&qbase[(qk * 32 + lo) * CDH + ks * 16 + hi * 8];

  // Staging sources (pre-XOR-swizzled chunk within each 128B row)
  const int srow = tid >> 3;
  const int soff = ((tid & 7) * 16) ^ ((srow & 7) << 4);
  const char* kb = (const char*)kp + (size_t)bh * CS * 128;
  const char* vb = (const char*)vtp + (size_t)bh * CDH * (CS * 2);
  const char* ksrc0 = kb + (size_t)srow * 128 + soff;
  const char* ksrc1 = kb + (size_t)(srow + 32) * 128 + soff;
  const char* vsrc0 = vb + (size_t)srow * (CS * 2) + soff;
  const char* vsrc1 = vb + (size_t)(srow + 32) * (CS * 2) + soff;

  const bf16x8 ones = {0x3F80, 0x3F80, 0x3F80, 0x3F80,
                       0x3F80, 0x3F80, 0x3F80, 0x3F80};

  f32x16 accO[2][2] = {};  // [stream][nb]
  f32x16 accS[2] = {};     // [stream]
  float mrun[2] = {-1e30f, -1e30f};

  // prologue: K[0]->Ks[0], K[1]->Ks[1], V[0]->Vs[0]
  gload16(ksrc0, (char*)&Ks[0][0] + tid * 16);
  gload16(ksrc1, (char*)&Ks[0][0] + tid * 16 + 4096);
  gload16(ksrc0 + 8192, (char*)&Ks[1][0] + tid * 16);
  gload16(ksrc1 + 8192, (char*)&Ks[1][0] + tid * 16 + 4096);
  gload16(vsrc0, (char*)&Vs[0][0] + tid * 16);
  gload16(vsrc1, (char*)&Vs[0][0] + tid * 16 + 4096);
  __syncthreads();

  f32x16 scA[2] = {};
  qk_half((const char*)&Ks[0][0], qf[0], scA, ctx);

  for (int to = 0; to < 32; to += 4) {
#pragma unroll
    for (int ti = 0; ti < 4; ++ti) {
      const int t = to + ti;  // Ks slot = ti, Vs slot = ti&1 (to % 4 == 0)
      const char* Kc = (const char*)&Ks[ti][0];
      const char* Kn = (const char*)&Ks[(ti + 1) & 3][0];
      const char* Vc = (const char*)&Vs[ti & 1][0];

      if (t < 30) {  // stage K[t+2]
        size_t ko = (size_t)(t + 2) * 8192;
        gload16(ksrc0 + ko, (char*)&Ks[(ti + 2) & 3][0] + tid * 16);
        gload16(ksrc1 + ko, (char*)&Ks[(ti + 2) & 3][0] + tid * 16 + 4096);
      }
      if (t < 31) {  // stage V[t+1]
        size_t vo = (size_t)(t + 1) * 128;
        gload16(vsrc0 + vo, (char*)&Vs[(ti + 1) & 1][0] + tid * 16);
        gload16(vsrc1 + vo, (char*)&Vs[(ti + 1) & 1][0] + tid * 16 + 4096);
      }

      f32x16 scB[2] = {};
      qk_half(Kc, qf[1], scB, ctx);                      // B: QK(t)
      smpv_half(scA, Vc, accO[0], accS[0], mrun[0], ones, ctx);  // A: SM+PV(t)
      if (t < 31) {
        f32x16 z0 = {}, z1 = {};
        f32x16 zz[2] = {z0, z1};
        qk_half(Kn, qf[0], zz, ctx);                     // A: QK(t+1)
        scA[0] = zz[0];
        scA[1] = zz[1];
      }
      smpv_half(scB, Vc, accO[1], accS[1], mrun[1], ones, ctx);  // B: SM+PV(t)
      __syncthreads();
    }
  }

  // epilogue: normalize (per-reg rcp of accS row-sum) and store
#pragma unroll
  for (int qk = 0; qk < 2; ++qk) {
    f32x16 iv;
#pragma unroll
    for (int r = 0; r < 16; ++r) iv[r] = rcpv(accS[qk][r]);
#pragma unroll
    for (int nb = 0; nb < 2; ++nb) {
      f32x16 val = accO[qk][nb] * iv;
#pragma unroll
      for (int r = 0; r < 16; ++r) {
        int sg = qb * 256 + w * 64 + qk * 32 + (r & 3) + 8 * (r >> 2) + 4 * hi;
        outp[((size_t)(b * CS + sg)) * CE + h * CDH + nb * 32 + lo] =
            f2bf(val[r]);
      }
    }
  }
}

extern "C" void kernel_launch(void* const* d_in, const int* in_sizes, int n_in,
                              void* d_out, int out_size, void* d_ws,
                              size_t ws_size, hipStream_t stream) {
  const float* queries = (const float*)d_in[0];
  const float* keys    = (const float*)d_in[1];
  const float* values  = (const float*)d_in[2];
  const float* Wq = (const float*)d_in[3];
  const float* bq = (const float*)d_in[4];
  const float* Wk = (const float*)d_in[5];
  const float* bk = (const float*)d_in[6];
  const float* Wv = (const float*)d_in[7];
  const float* bv = (const float*)d_in[8];
  const float* Wo = (const float*)d_in[9];
  const float* bo = (const float*)d_in[10];

  const size_t NELT = (size_t)CB * CS * CE;  // 8388608
  short* R1  = (short*)d_ws;        // attn output (bf16 [B,S,E])
  short* qp  = R1 + NELT;
  short* kp  = qp + NELT;
  short* vtp = kp + NELT;
  // W16 scratch lives in d_out (dead until the final GEMM overwrites it)
  short* w16q = (short*)d_out;
  short* w16k = w16q + (size_t)CE * CE;
  short* w16v = w16k + (size_t)CE * CE;

  dim3 blk(256);
  const float qscale = 0.18033688011112042f;  // log2(e) / sqrt(DH)

  cvtW3<<<dim3(512, 3), blk, 0, stream>>>(Wq, Wk, Wv, w16q, w16k, w16v);
  gemm_qkv<<<dim3(512, 3), blk, 0, stream>>>(
      queries, keys, values, w16q, w16k, w16v, bq, bk, bv, qp, kp, vtp,
      qscale);
  attn_fwd<<<512, blk, 0, stream>>>(qp, kp, vtp, R1);
  gemm_out<<<512, blk, 0, stream>>>(R1, Wo, bo, (float*)d_out, CE);
}